// Round 1
// baseline (619.727 us; speedup 1.0000x reference)
//
#include <hip/hip_runtime.h>

// UpBlock: deconv(8-oct GEMM) -> BN+ELU -> 27-tap gather conv -> BN+ELU
// bf16 MFMA 16x16x32 pipeline; BN stats via binned f32 atomics.

#define N_PARENT 65536
#define C_IN     128
#define C_OUT    64
#define N_CHILD  (N_PARENT * 8)
#define TAPS     27
#define NBINS    64

typedef __bf16 bf16x8 __attribute__((ext_vector_type(8)));
typedef float  f32x4  __attribute__((ext_vector_type(4)));

// workspace layout (bytes)
#define Y_OFF     0u               // bf16 y [N_CHILD][64]  = 67108864
#define WTUP_OFF  67108864u        // bf16 WtUp [8][64 n][128 k] = 131072
#define WTCV_OFF  67239936u        // bf16 WtCv [27][64 n][64 k] = 221184
#define S1_OFF    67461120u        // f32 bins1 [64][128]   = 32768
#define S2_OFF    67493888u        // f32 bins2 [64][128]   = 32768
#define AB1_OFF   67526656u        // f32 a1[64], b1[64]    = 512
#define AB2_OFF   67527168u        // f32 a2[64], b2[64]    = 512

__device__ __forceinline__ float elu_f(float f) {
    return f > 0.f ? f : (__expf(f) - 1.f);
}

// ---- prep: transpose weights to [n][k] layout, cast to bf16 ----
__global__ __launch_bounds__(256) void prep_w(const float* __restrict__ wup,
                                              const float* __restrict__ wcv,
                                              __bf16* __restrict__ wtup,
                                              __bf16* __restrict__ wtcv) {
    int i = blockIdx.x * 256 + threadIdx.x;
    if (i < 8 * 64 * 128) {
        int o = i >> 13, rem = i & 8191, n = rem >> 7, k = rem & 127;
        wtup[i] = (__bf16)wup[o * 8192 + k * 64 + n];
    } else {
        int j = i - 65536;                     // j < 27*64*64 = 110592
        int t = j >> 12, rem = j & 4095, n = rem >> 6, k = rem & 63;
        wtcv[j] = (__bf16)wcv[t * 4096 + k * 64 + n];
    }
}

// ---- kernel A: y[8p+oct] = x[p] @ W_up[oct], accumulate BN1 stats ----
// block: 256 thr (4 waves); block handles 16 parents x 8 octants.
// wave w does octants {2w, 2w+1}; per-wave tile 16 parents x 64 cols.
__global__ __launch_bounds__(256) void deconv_bn_stats(
    const float* __restrict__ x, const __bf16* __restrict__ wtup,
    __bf16* __restrict__ y, float* __restrict__ bins) {
    __shared__ float ssum[64], ssq[64];
    int tid = threadIdx.x;
    int wave = tid >> 6, lane = tid & 63, lr = lane & 15, lg = lane >> 4;
    int p0 = blockIdx.x * 16;

    if (tid < 64) { ssum[tid] = 0.f; ssq[tid] = 0.f; }

    // A-fragments: x row (f32 -> bf16), k = ks*32 + lg*8 + i
    const float* xrow = x + (size_t)(p0 + lr) * C_IN;
    bf16x8 afr[4];
#pragma unroll
    for (int ks = 0; ks < 4; ++ks) {
        const float* src = xrow + ks * 32 + lg * 8;
        f32x4 u0 = *(const f32x4*)(src);
        f32x4 u1 = *(const f32x4*)(src + 4);
        bf16x8 a;
#pragma unroll
        for (int i = 0; i < 4; ++i) { a[i] = (__bf16)u0[i]; a[4 + i] = (__bf16)u1[i]; }
        afr[ks] = a;
    }

    float lsum[4] = {0.f, 0.f, 0.f, 0.f}, lsq[4] = {0.f, 0.f, 0.f, 0.f};
#pragma unroll
    for (int oo = 0; oo < 2; ++oo) {
        int oct = wave * 2 + oo;
#pragma unroll
        for (int nt = 0; nt < 4; ++nt) {
            f32x4 acc = {0.f, 0.f, 0.f, 0.f};
#pragma unroll
            for (int ks = 0; ks < 4; ++ks) {
                const __bf16* bp = wtup + ((size_t)(oct * 64 + nt * 16 + lr) * C_IN + ks * 32 + lg * 8);
                bf16x8 b = *(const bf16x8*)bp;
                acc = __builtin_amdgcn_mfma_f32_16x16x32_bf16(afr[ks], b, acc, 0, 0, 0);
            }
#pragma unroll
            for (int r = 0; r < 4; ++r) {
                int parent = p0 + lg * 4 + r;
                int child = parent * 8 + oct;
                float v = acc[r];
                y[(size_t)child * C_OUT + nt * 16 + lr] = (__bf16)v;
                lsum[nt] += v; lsq[nt] += v * v;
            }
        }
    }
    __syncthreads();
#pragma unroll
    for (int nt = 0; nt < 4; ++nt) {
        atomicAdd(&ssum[nt * 16 + lr], lsum[nt]);
        atomicAdd(&ssq[nt * 16 + lr], lsq[nt]);
    }
    __syncthreads();
    if (tid < 64) {
        float* b = bins + (size_t)(blockIdx.x & (NBINS - 1)) * 128;
        atomicAdd(&b[tid], ssum[tid]);
        atomicAdd(&b[64 + tid], ssq[tid]);
    }
}

// ---- finalize: per-channel a = gamma*rstd, b = beta - mu*a ----
__global__ void finalize_stats(const float* __restrict__ bins,
                               const float* __restrict__ gamma,
                               const float* __restrict__ beta,
                               float* __restrict__ ab, float invN) {
    int c = threadIdx.x;  // 64 threads
    float s = 0.f, q = 0.f;
    for (int b = 0; b < NBINS; ++b) { s += bins[b * 128 + c]; q += bins[b * 128 + 64 + c]; }
    float mu = s * invN;
    float var = q * invN - mu * mu;
    float rstd = rsqrtf(var + 1e-5f);
    float a = gamma[c] * rstd;
    ab[c] = a;
    ab[64 + c] = beta[c] - mu * a;
}

// ---- BN1 + ELU applied in place on bf16 y ----
__global__ __launch_bounds__(256) void bn_elu_y(__bf16* __restrict__ y,
                                                const float* __restrict__ ab) {
    int tid = blockIdx.x * 256 + threadIdx.x;   // 4096*256 = 1048576 threads
    int c0 = (tid * 8) & 63;
    float av[8], bv[8];
#pragma unroll
    for (int j = 0; j < 8; ++j) { av[j] = ab[c0 + j]; bv[j] = ab[64 + c0 + j]; }
#pragma unroll
    for (int t = 0; t < 4; ++t) {
        size_t e = ((size_t)t * 1048576 + tid) * 8;
        bf16x8 v = *(const bf16x8*)(y + e);
        bf16x8 o;
#pragma unroll
        for (int j = 0; j < 8; ++j) {
            float f = (float)v[j] * av[j] + bv[j];
            o[j] = (__bf16)elu_f(f);
        }
        *(bf16x8*)(y + e) = o;
    }
}

// ---- kernel C: 27-tap gather conv, raw acc -> d_out (f32), BN2 stats ----
// block: 256 thr (4 waves); each wave owns 64 rows x 64 cols (4 M-tiles).
__global__ __launch_bounds__(256) void conv_bn_stats(
    const __bf16* __restrict__ y, const int* __restrict__ neigh,
    const __bf16* __restrict__ wtcv, float* __restrict__ out,
    float* __restrict__ bins) {
    __shared__ float ssum[64], ssq[64];
    int tid = threadIdx.x;
    int wave = tid >> 6, lane = tid & 63, lr = lane & 15, lg = lane >> 4;
    int base = blockIdx.x * 256 + wave * 64;

    if (tid < 64) { ssum[tid] = 0.f; ssq[tid] = 0.f; }

    f32x4 acc[4][4];
#pragma unroll
    for (int mt = 0; mt < 4; ++mt)
#pragma unroll
        for (int nt = 0; nt < 4; ++nt) acc[mt][nt] = (f32x4){0.f, 0.f, 0.f, 0.f};

    int rown[4], idx[4];
#pragma unroll
    for (int mt = 0; mt < 4; ++mt) rown[mt] = (base + mt * 16 + lr) * TAPS;
#pragma unroll
    for (int mt = 0; mt < 4; ++mt) idx[mt] = neigh[rown[mt]];

    for (int k = 0; k < TAPS; ++k) {
        int nidx[4];
        if (k < TAPS - 1) {
#pragma unroll
            for (int mt = 0; mt < 4; ++mt) nidx[mt] = neigh[rown[mt] + k + 1];
        }
        const __bf16* wk = wtcv + (size_t)k * 4096;
#pragma unroll
        for (int ks = 0; ks < 2; ++ks) {
            bf16x8 af[4], bfr[4];
#pragma unroll
            for (int mt = 0; mt < 4; ++mt)
                af[mt] = *(const bf16x8*)(y + (size_t)idx[mt] * C_OUT + ks * 32 + lg * 8);
#pragma unroll
            for (int nt = 0; nt < 4; ++nt)
                bfr[nt] = *(const bf16x8*)(wk + (nt * 16 + lr) * 64 + ks * 32 + lg * 8);
#pragma unroll
            for (int mt = 0; mt < 4; ++mt)
#pragma unroll
                for (int nt = 0; nt < 4; ++nt)
                    acc[mt][nt] = __builtin_amdgcn_mfma_f32_16x16x32_bf16(af[mt], bfr[nt], acc[mt][nt], 0, 0, 0);
        }
#pragma unroll
        for (int mt = 0; mt < 4; ++mt) idx[mt] = nidx[mt];
    }

    float lsum[4] = {0.f, 0.f, 0.f, 0.f}, lsq[4] = {0.f, 0.f, 0.f, 0.f};
#pragma unroll
    for (int mt = 0; mt < 4; ++mt)
#pragma unroll
        for (int nt = 0; nt < 4; ++nt)
#pragma unroll
            for (int r = 0; r < 4; ++r) {
                float v = acc[mt][nt][r];
                int row = base + mt * 16 + lg * 4 + r;
                out[(size_t)row * C_OUT + nt * 16 + lr] = v;
                lsum[nt] += v; lsq[nt] += v * v;
            }
    __syncthreads();
#pragma unroll
    for (int nt = 0; nt < 4; ++nt) {
        atomicAdd(&ssum[nt * 16 + lr], lsum[nt]);
        atomicAdd(&ssq[nt * 16 + lr], lsq[nt]);
    }
    __syncthreads();
    if (tid < 64) {
        float* b = bins + (size_t)(blockIdx.x & (NBINS - 1)) * 128;
        atomicAdd(&b[tid], ssum[tid]);
        atomicAdd(&b[64 + tid], ssq[tid]);
    }
}

// ---- BN2 + ELU applied in place on f32 d_out ----
__global__ __launch_bounds__(256) void bn_elu_out(float* __restrict__ out,
                                                  const float* __restrict__ ab) {
    int tid = blockIdx.x * 256 + threadIdx.x;   // 1048576 threads
    int c0 = (tid * 4) & 63;
    float av[4], bv[4];
#pragma unroll
    for (int j = 0; j < 4; ++j) { av[j] = ab[c0 + j]; bv[j] = ab[64 + c0 + j]; }
#pragma unroll
    for (int t = 0; t < 8; ++t) {
        size_t e = ((size_t)t * 1048576 + tid) * 4;
        f32x4 v = *(const f32x4*)(out + e);
        f32x4 o;
#pragma unroll
        for (int j = 0; j < 4; ++j) o[j] = elu_f(v[j] * av[j] + bv[j]);
        *(f32x4*)(out + e) = o;
    }
}

extern "C" void kernel_launch(void* const* d_in, const int* in_sizes, int n_in,
                              void* d_out, int out_size, void* d_ws, size_t ws_size,
                              hipStream_t stream) {
    const float* x     = (const float*)d_in[0];
    const int*   neigh = (const int*)d_in[1];
    const float* wup   = (const float*)d_in[2];
    const float* wcv   = (const float*)d_in[3];
    const float* g1    = (const float*)d_in[4];
    const float* b1    = (const float*)d_in[5];
    const float* g2    = (const float*)d_in[6];
    const float* b2    = (const float*)d_in[7];
    float* out = (float*)d_out;

    char* ws = (char*)d_ws;
    __bf16* y     = (__bf16*)(ws + Y_OFF);
    __bf16* wtup  = (__bf16*)(ws + WTUP_OFF);
    __bf16* wtcv  = (__bf16*)(ws + WTCV_OFF);
    float*  bins1 = (float*)(ws + S1_OFF);
    float*  bins2 = (float*)(ws + S2_OFF);
    float*  ab1   = (float*)(ws + AB1_OFF);
    float*  ab2   = (float*)(ws + AB2_OFF);

    // zero stats bins + ab (contiguous region)
    hipMemsetAsync(ws + S1_OFF, 0, 32768u * 2 + 1024u, stream);

    prep_w<<<688, 256, 0, stream>>>(wup, wcv, wtup, wtcv);
    deconv_bn_stats<<<N_PARENT / 16, 256, 0, stream>>>(x, wtup, y, bins1);
    finalize_stats<<<1, 64, 0, stream>>>(bins1, g1, b1, ab1, 1.f / (float)N_CHILD);
    bn_elu_y<<<4096, 256, 0, stream>>>(y, ab1);
    conv_bn_stats<<<N_CHILD / 256, 256, 0, stream>>>(y, neigh, wtcv, out, bins2);
    finalize_stats<<<1, 64, 0, stream>>>(bins2, g2, b2, ab2, 1.f / (float)N_CHILD);
    bn_elu_out<<<4096, 256, 0, stream>>>(out, ab2);
}